// Round 1
// baseline (934.659 us; speedup 1.0000x reference)
//
#include <hip/hip_runtime.h>
#include <hip/hip_bf16.h>

// S5 layer: B=16, L=4096, H=256, P=256 (fp32 in/out)
// Decomposition: K0 precompute -> per 4-batch segment: K1 (Bu GEMM + local chunk scan),
// K2 (cross-chunk state chain), K3 (x reconstruct + output GEMM + D*u).

#define P_ 256
#define H_ 256
#define B_ 16
#define L_ 4096
#define LC 32
#define NC (L_/LC)      // 128 chunks
#define SEG 4           // batches per segment (caps ws at ~20 MB)
#define NSEG (B_/SEG)

static __device__ __forceinline__ unsigned pack_bf16x2(float a, float b) {
    unsigned ua = __float_as_uint(a);
    unsigned ub = __float_as_uint(b);
    ua = (ua + 0x7fffu + ((ua >> 16) & 1u)) >> 16;   // round-to-nearest-even
    ub = (ub + 0x7fffu + ((ub >> 16) & 1u)) >> 16;
    return ua | (ub << 16);
}

// ---------------- K0: discretization + operand transposes ----------------
__global__ __launch_bounds__(256) void k0_pre(
    const float* __restrict__ Lre, const float* __restrict__ Lim,
    const float* __restrict__ Bre, const float* __restrict__ Bim,
    const float* __restrict__ Cre, const float* __restrict__ Cim,
    const float* __restrict__ lstep,
    float* __restrict__ lam, float* __restrict__ lamLc,
    float* __restrict__ Bbt_re, float* __restrict__ Bbt_im,
    float* __restrict__ Ct2_re, float* __restrict__ Ct2_im)
{
    int h = blockIdx.x;   // 0..H-1
    int p = threadIdx.x;  // 0..P-1
    float laR = Lre[p], laI = Lim[p];
    float st = expf(lstep[p]);                 // STEP_RESCALE = 1
    float er = expf(laR * st);
    float lr = er * cosf(laI * st);            // Lambda_bar
    float li = er * sinf(laI * st);
    float den = laR * laR + laI * laI;
    float nr = lr - 1.0f, ni = li;             // Lambda_bar - 1
    float cr = (nr * laR + ni * laI) / den;    // (Lbar-1)/Lambda
    float ci = (ni * laR - nr * laI) / den;
    float br = Bre[(size_t)p * H_ + h], bi = Bim[(size_t)p * H_ + h];
    Bbt_re[h * P_ + p] = cr * br - ci * bi;    // B_bar transposed [h][p]
    Bbt_im[h * P_ + p] = cr * bi + ci * br;
    Ct2_re[p * H_ + h] =  2.0f * Cre[h * P_ + p];   // C transposed [p][h], 2x folded
    Ct2_im[p * H_ + h] = -2.0f * Cim[h * P_ + p];   // minus folded (Re of product)
    if (h == 0) {
        lam[2 * p] = lr; lam[2 * p + 1] = li;
        float pr = 1.0f, pi = 0.0f;
        #pragma unroll
        for (int k = 0; k < LC; ++k) {
            float t = pr * lr - pi * li;
            pi = pr * li + pi * lr;
            pr = t;
        }
        lamLc[2 * p] = pr; lamLc[2 * p + 1] = pi;  // Lambda_bar^LC
    }
}

// ---------------- K1: Bu GEMM + local scan (zero init), store x_loc(bf16) + finals ---
__global__ __launch_bounds__(256) void k1_buscan(
    const float* __restrict__ u,
    const float* __restrict__ Bbt_re, const float* __restrict__ Bbt_im,
    const float* __restrict__ lam,
    unsigned* __restrict__ xloc,       // [SEG][L][P] packed bf16 (re,im)
    float2* __restrict__ sfin,         // [SEG][NC][P]
    int b0)
{
    __shared__ float us[LC * H_];      // 32 KB u chunk, [j][h]
    int tid = threadIdx.x;
    int c  = blockIdx.x & (NC - 1);
    int bl = blockIdx.x / NC;          // 0..SEG-1
    int b  = b0 + bl;

    const float4* ub4 = (const float4*)(u + ((size_t)(b * L_ + c * LC)) * H_);
    float4* us4 = (float4*)us;
    #pragma unroll
    for (int i = 0; i < 8; ++i) us4[i * 256 + tid] = ub4[i * 256 + tid];
    __syncthreads();

    int p = tid;
    float accr[LC], acci[LC];
    #pragma unroll
    for (int j = 0; j < LC; ++j) { accr[j] = 0.f; acci[j] = 0.f; }

    for (int h4 = 0; h4 < H_ / 4; ++h4) {
        float br0 = Bbt_re[(h4 * 4 + 0) * P_ + p];
        float br1 = Bbt_re[(h4 * 4 + 1) * P_ + p];
        float br2 = Bbt_re[(h4 * 4 + 2) * P_ + p];
        float br3 = Bbt_re[(h4 * 4 + 3) * P_ + p];
        float bi0 = Bbt_im[(h4 * 4 + 0) * P_ + p];
        float bi1 = Bbt_im[(h4 * 4 + 1) * P_ + p];
        float bi2 = Bbt_im[(h4 * 4 + 2) * P_ + p];
        float bi3 = Bbt_im[(h4 * 4 + 3) * P_ + p];
        #pragma unroll
        for (int j = 0; j < LC; ++j) {
            float4 uu = *(const float4*)&us[j * H_ + h4 * 4];  // wave-uniform broadcast
            accr[j] += uu.x * br0 + uu.y * br1 + uu.z * br2 + uu.w * br3;
            acci[j] += uu.x * bi0 + uu.y * bi1 + uu.z * bi2 + uu.w * bi3;
        }
    }

    float lr = lam[2 * p], li = lam[2 * p + 1];
    float xr = 0.f, xi = 0.f;
    unsigned* xl = xloc + ((size_t)(bl * L_ + c * LC)) * P_ + p;
    #pragma unroll
    for (int j = 0; j < LC; ++j) {
        float nxr = lr * xr - li * xi + accr[j];
        float nxi = lr * xi + li * xr + acci[j];
        xr = nxr; xi = nxi;
        xl[(size_t)j * P_] = pack_bf16x2(xr, xi);
    }
    sfin[(bl * NC + c) * P_ + p] = make_float2(xr, xi);
}

// ---------------- K2: cross-chunk state chain ----------------
__global__ __launch_bounds__(256) void k2_chain(
    const float* __restrict__ lamLc,
    const float2* __restrict__ sfin,
    float2* __restrict__ sinv)
{
    int bl = blockIdx.x;       // 0..SEG-1
    int p = threadIdx.x;
    float ar = lamLc[2 * p], ai = lamLc[2 * p + 1];
    float sr = 0.f, si = 0.f;
    const float2* sf = sfin + (size_t)bl * NC * P_ + p;
    float2* sn = sinv + (size_t)bl * NC * P_ + p;
    for (int c = 0; c < NC; ++c) {
        sn[(size_t)c * P_] = make_float2(sr, si);
        float2 f = sf[(size_t)c * P_];
        float nr = ar * sr - ai * si + f.x;
        float ni = ar * si + ai * sr + f.y;
        sr = nr; si = ni;
    }
}

// ---------------- K3: reconstruct x, output GEMM, +D*u ----------------
__global__ __launch_bounds__(256) void k3_out(
    const float* __restrict__ u,
    const unsigned* __restrict__ xloc,
    const float2* __restrict__ sinv,
    const float* __restrict__ lam,
    const float* __restrict__ Ct2_re, const float* __restrict__ Ct2_im,
    const float* __restrict__ Dv,
    float* __restrict__ out,
    int b0)
{
    __shared__ float2 xs[LC * P_];     // 64 KB corrected states [j][p]
    int tid = threadIdx.x;
    int c  = blockIdx.x & (NC - 1);
    int bl = blockIdx.x / NC;
    int b  = b0 + bl;

    {
        int p = tid;
        float lr = lam[2 * p], li = lam[2 * p + 1];
        float2 s0 = sinv[(bl * NC + c) * P_ + p];
        float gr = lr, gi = li;        // lam^(j+1)
        const unsigned* xl = xloc + ((size_t)(bl * L_ + c * LC)) * P_ + p;
        #pragma unroll
        for (int j = 0; j < LC; ++j) {
            unsigned w = xl[(size_t)j * P_];
            float xr = __uint_as_float(w << 16);
            float xi = __uint_as_float(w & 0xffff0000u);
            xr += gr * s0.x - gi * s0.y;
            xi += gr * s0.y + gi * s0.x;
            xs[j * P_ + p] = make_float2(xr, xi);
            float t = gr * lr - gi * li;
            gi = gr * li + gi * lr;
            gr = t;
        }
    }
    __syncthreads();

    int h = tid;
    float yacc[LC];
    #pragma unroll
    for (int j = 0; j < LC; ++j) yacc[j] = 0.f;

    for (int p4 = 0; p4 < P_ / 4; ++p4) {
        float cr0 = Ct2_re[(p4 * 4 + 0) * H_ + h];
        float cr1 = Ct2_re[(p4 * 4 + 1) * H_ + h];
        float cr2 = Ct2_re[(p4 * 4 + 2) * H_ + h];
        float cr3 = Ct2_re[(p4 * 4 + 3) * H_ + h];
        float ci0 = Ct2_im[(p4 * 4 + 0) * H_ + h];
        float ci1 = Ct2_im[(p4 * 4 + 1) * H_ + h];
        float ci2 = Ct2_im[(p4 * 4 + 2) * H_ + h];
        float ci3 = Ct2_im[(p4 * 4 + 3) * H_ + h];
        #pragma unroll
        for (int j = 0; j < LC; ++j) {
            float4 a  = *(const float4*)&xs[j * P_ + p4 * 4];      // p0,p1 (re,im)
            float4 bq = *(const float4*)&xs[j * P_ + p4 * 4 + 2];  // p2,p3
            yacc[j] += a.x * cr0 + a.y * ci0 + a.z * cr1 + a.w * ci1;
            yacc[j] += bq.x * cr2 + bq.y * ci2 + bq.z * cr3 + bq.w * ci3;
        }
    }

    float Dh = Dv[h];
    const float* ubp = u + ((size_t)(b * L_ + c * LC)) * H_;
    float* obp = out + ((size_t)(b * L_ + c * LC)) * H_;
    #pragma unroll
    for (int j = 0; j < LC; ++j) {
        obp[j * H_ + h] = yacc[j] + Dh * ubp[j * H_ + h];
    }
}

// ---------------- launch ----------------
extern "C" void kernel_launch(void* const* d_in, const int* in_sizes, int n_in,
                              void* d_out, int out_size, void* d_ws, size_t ws_size,
                              hipStream_t stream) {
    (void)in_sizes; (void)n_in; (void)out_size; (void)ws_size;
    const float* u    = (const float*)d_in[0];
    const float* Lre  = (const float*)d_in[1];
    const float* Lim  = (const float*)d_in[2];
    const float* Bre  = (const float*)d_in[3];
    const float* Bim  = (const float*)d_in[4];
    const float* Cre  = (const float*)d_in[5];
    const float* Cim  = (const float*)d_in[6];
    const float* Dv   = (const float*)d_in[7];
    const float* lstep= (const float*)d_in[8];

    float* ws     = (float*)d_ws;
    float* lam    = ws;                         // 2*P
    float* lamLc  = lam + 2 * P_;               // 2*P
    float* Bbt_re = lamLc + 2 * P_;             // H*P
    float* Bbt_im = Bbt_re + H_ * P_;           // H*P
    float* Ct2_re = Bbt_im + H_ * P_;           // P*H
    float* Ct2_im = Ct2_re + P_ * H_;           // P*H
    float* sfin   = Ct2_im + P_ * H_;           // 2*SEG*NC*P
    float* sinv   = sfin + 2 * SEG * NC * P_;   // 2*SEG*NC*P
    unsigned* xloc = (unsigned*)(sinv + 2 * SEG * NC * P_);  // SEG*L*P uints (16.8 MB)

    k0_pre<<<H_, 256, 0, stream>>>(Lre, Lim, Bre, Bim, Cre, Cim, lstep,
                                   lam, lamLc, Bbt_re, Bbt_im, Ct2_re, Ct2_im);
    for (int s = 0; s < NSEG; ++s) {
        k1_buscan<<<SEG * NC, 256, 0, stream>>>(u, Bbt_re, Bbt_im, lam,
                                                xloc, (float2*)sfin, s * SEG);
        k2_chain<<<SEG, 256, 0, stream>>>(lamLc, (const float2*)sfin, (float2*)sinv);
        k3_out<<<SEG * NC, 256, 0, stream>>>(u, xloc, (const float2*)sinv, lam,
                                             Ct2_re, Ct2_im, Dv, (float*)d_out, s * SEG);
    }
}

// Round 2
// 193.009 us; speedup vs baseline: 4.8426x; 4.8426x over previous
//
#include <hip/hip_runtime.h>
#include <hip/hip_bf16.h>

// S5 layer, MFMA pipeline: K0 precompute -> per 4-batch segment:
//   KU (u->bf16), G1 (MFMA Bu GEMM), S1 (chunk finals), S2 (chain),
//   S3 (full scan -> x bf16), G2 (MFMA output GEMM + D*u).

#define P_ 256
#define H_ 256
#define B_ 16
#define L_ 4096
#define LC 64
#define NC (L_/LC)          // 64 chunks
#define SEG 4               // batches per segment
#define NSEG (B_/SEG)
#define MSEG (SEG*L_)       // 16384 rows per segment

typedef __attribute__((ext_vector_type(8))) short short8v;
typedef __attribute__((ext_vector_type(4))) float f32x4;

#define GLOBAL_AS __attribute__((address_space(1)))
#define LDS_AS __attribute__((address_space(3)))

static __device__ __forceinline__ void gl_lds16(const void* g, void* l) {
    __builtin_amdgcn_global_load_lds((const GLOBAL_AS unsigned char*)g,
                                     (LDS_AS unsigned char*)l, 16, 0, 0);
}

static __device__ __forceinline__ unsigned pack_bf16x2(float a, float b) {
    unsigned ua = __float_as_uint(a);
    unsigned ub = __float_as_uint(b);
    ua = (ua + 0x7fffu + ((ua >> 16) & 1u)) >> 16;   // RNE
    ub = (ub + 0x7fffu + ((ub >> 16) & 1u)) >> 16;
    return ua | (ub << 16);
}

static __device__ __forceinline__ unsigned short f2bf(float f) {
    unsigned u = __float_as_uint(f);
    return (unsigned short)((u + 0x7fffu + ((u >> 16) & 1u)) >> 16);
}

// ---------------- K0: discretization + bf16 operand layouts ----------------
// B1op [2P][H] bf16: row 2p = Bbar_re[p][:], row 2p+1 = Bbar_im[p][:]
// C2op [H][2P] bf16: [h][2p] = 2*Cre[h][p], [h][2p+1] = -2*Cim[h][p]
__global__ __launch_bounds__(256) void k0_pre(
    const float* __restrict__ Lre, const float* __restrict__ Lim,
    const float* __restrict__ Bre, const float* __restrict__ Bim,
    const float* __restrict__ Cre, const float* __restrict__ Cim,
    const float* __restrict__ lstep,
    float* __restrict__ lam, float* __restrict__ lamLc,
    unsigned short* __restrict__ B1op, unsigned short* __restrict__ C2op)
{
    int bx = blockIdx.x;   // doubles as p (B-part) and h (C-part)
    int t  = threadIdx.x;
    {
        int p = bx, h = t;
        float laR = Lre[p], laI = Lim[p];
        float st = expf(lstep[p]);
        float er = expf(laR * st);
        float lr = er * cosf(laI * st);
        float li = er * sinf(laI * st);
        float den = laR * laR + laI * laI;
        float nr = lr - 1.0f, ni = li;
        float cr = (nr * laR + ni * laI) / den;
        float ci = (ni * laR - nr * laI) / den;
        float br = Bre[p * H_ + h], bi = Bim[p * H_ + h];
        B1op[(2 * p) * H_ + h]     = f2bf(cr * br - ci * bi);
        B1op[(2 * p + 1) * H_ + h] = f2bf(cr * bi + ci * br);
        if (t == 0) {
            lam[2 * p] = lr; lam[2 * p + 1] = li;
            float pr = 1.0f, pi = 0.0f;
            #pragma unroll
            for (int k = 0; k < LC; ++k) {
                float tt = pr * lr - pi * li;
                pi = pr * li + pi * lr;
                pr = tt;
            }
            lamLc[2 * p] = pr; lamLc[2 * p + 1] = pi;
        }
    }
    {
        int h = bx, p = t;
        C2op[(size_t)h * 512 + 2 * p]     = f2bf( 2.0f * Cre[h * P_ + p]);
        C2op[(size_t)h * 512 + 2 * p + 1] = f2bf(-2.0f * Cim[h * P_ + p]);
    }
}

// ---------------- KU: u fp32 -> bf16 (one segment) ----------------
__global__ __launch_bounds__(256) void ku_conv(const float* __restrict__ u,
                                               unsigned short* __restrict__ ub)
{
    int i = blockIdx.x * 256 + threadIdx.x;    // over float4s: MSEG*H/4
    float4 v = ((const float4*)u)[i];
    uint2 o;
    o.x = (unsigned)f2bf(v.x) | ((unsigned)f2bf(v.y) << 16);
    o.y = (unsigned)f2bf(v.z) | ((unsigned)f2bf(v.w) << 16);
    ((uint2*)ub)[i] = o;
}

// ---------------- G1: Bu = u_bf * B1op^T, output packed bf16 pairs ----------
// A: ub [MSEG][256] bf16; B: B1op [512][256] bf16 (row = out col, K-contig)
// C: Bu [MSEG][256] dwords (each dword = packed (re,im) bf16 for one p)
__global__ __launch_bounds__(256) void g1_gemm(
    const unsigned short* __restrict__ ub,
    const unsigned short* __restrict__ B1op,
    unsigned* __restrict__ Bu)
{
    __shared__ char smem[33280];
    unsigned short* Al = (unsigned short*)smem;            // [128][64] swizzled
    unsigned short* Bl = (unsigned short*)(smem + 16384);  // [128][64] swizzled
    float* epl = (float*)smem;                             // [64][130] epilogue

    int tid = threadIdx.x, w = tid >> 6, lane = tid & 63;
    int wr = w >> 1, wc = w & 1;
    int m0 = blockIdx.x * 128;
    int n0 = blockIdx.y * 128;
    int lr_ = lane & 15, lk = lane >> 4;

    f32x4 acc[4][4];
    #pragma unroll
    for (int m = 0; m < 4; ++m)
        #pragma unroll
        for (int n = 0; n < 4; ++n)
            acc[m][n] = (f32x4){0.f, 0.f, 0.f, 0.f};

    int sw8 = ((lane & 7) ^ ((lane >> 3) & 7)) * 8;   // pre-swizzled src k-offset
    for (int kt = 0; kt < 4; ++kt) {
        int k0 = kt * 64;
        #pragma unroll
        for (int i = 0; i < 4; ++i) {
            int blk = i * 4 + w;
            int r = blk * 8 + (lane >> 3);
            gl_lds16(ub   + (size_t)(m0 + r) * 256 + k0 + sw8, Al + blk * 512);
            gl_lds16(B1op + (size_t)(n0 + r) * 256 + k0 + sw8, Bl + blk * 512);
        }
        __syncthreads();
        #pragma unroll
        for (int kk = 0; kk < 2; ++kk) {
            short8v a_[4], b_[4];
            #pragma unroll
            for (int m = 0; m < 4; ++m) {
                int row = wr * 64 + m * 16 + lr_;
                a_[m] = *(const short8v*)&Al[row * 64 + (((lk + 4 * kk) ^ (lr_ & 7)) * 8)];
            }
            #pragma unroll
            for (int n = 0; n < 4; ++n) {
                int row = wc * 64 + n * 16 + lr_;
                b_[n] = *(const short8v*)&Bl[row * 64 + (((lk + 4 * kk) ^ (lr_ & 7)) * 8)];
            }
            #pragma unroll
            for (int m = 0; m < 4; ++m)
                #pragma unroll
                for (int n = 0; n < 4; ++n)
                    acc[m][n] = __builtin_amdgcn_mfma_f32_16x16x32_bf16(a_[m], b_[n], acc[m][n], 0, 0, 0);
        }
        __syncthreads();
    }

    // epilogue: repack adjacent (re,im) cols into dwords via LDS
    int n0d = blockIdx.y * 64;
    #pragma unroll
    for (int ph = 0; ph < 2; ++ph) {
        if (wr == ph) {
            #pragma unroll
            for (int m = 0; m < 4; ++m)
                #pragma unroll
                for (int n = 0; n < 4; ++n)
                    #pragma unroll
                    for (int i = 0; i < 4; ++i) {
                        int r = m * 16 + lk * 4 + i;          // 0..63
                        int c = wc * 64 + n * 16 + lr_;       // 0..127
                        epl[r * 130 + c] = acc[m][n][i];
                    }
        }
        __syncthreads();
        #pragma unroll
        for (int it = 0; it < 16; ++it) {
            int r = it * 4 + w;
            int q = lane;
            float2 v = *(const float2*)&epl[r * 130 + 2 * q];
            Bu[(size_t)(m0 + ph * 64 + r) * 256 + n0d + q] = pack_bf16x2(v.x, v.y);
        }
        __syncthreads();
    }
}

// ---------------- S1: chunk-local scan (zero init), finals only ------------
__global__ __launch_bounds__(256) void s1_scan(
    const unsigned* __restrict__ Bu, const float* __restrict__ lam,
    float2* __restrict__ sfin)
{
    int c = blockIdx.x & (NC - 1), bl = blockIdx.x / NC;
    int p = threadIdx.x;
    float lr = lam[2 * p], li = lam[2 * p + 1];
    const unsigned* bp = Bu + ((size_t)(bl * L_ + c * LC)) * 256 + p;
    float xr = 0.f, xi = 0.f;
    #pragma unroll 8
    for (int j = 0; j < LC; ++j) {
        unsigned wv = bp[(size_t)j * 256];
        float ur = __uint_as_float(wv << 16);
        float ui = __uint_as_float(wv & 0xffff0000u);
        float nr = lr * xr - li * xi + ur;
        float ni = lr * xi + li * xr + ui;
        xr = nr; xi = ni;
    }
    sfin[(bl * NC + c) * P_ + p] = make_float2(xr, xi);
}

// ---------------- S2: cross-chunk chain ----------------
__global__ __launch_bounds__(256) void s2_chain(
    const float* __restrict__ lamLc, const float2* __restrict__ sfin,
    float2* __restrict__ sinv)
{
    int bl = blockIdx.x;
    int p = threadIdx.x;
    float ar = lamLc[2 * p], ai = lamLc[2 * p + 1];
    float sr = 0.f, si = 0.f;
    #pragma unroll 8
    for (int c = 0; c < NC; ++c) {
        sinv[(bl * NC + c) * P_ + p] = make_float2(sr, si);
        float2 f = sfin[(bl * NC + c) * P_ + p];
        float nr = ar * sr - ai * si + f.x;
        float ni = ar * si + ai * sr + f.y;
        sr = nr; si = ni;
    }
}

// ---------------- S3: full scan with incoming state, write x bf16 ----------
__global__ __launch_bounds__(256) void s3_scan(
    const unsigned* __restrict__ Bu, const float* __restrict__ lam,
    const float2* __restrict__ sinv, unsigned* __restrict__ xb)
{
    int c = blockIdx.x & (NC - 1), bl = blockIdx.x / NC;
    int p = threadIdx.x;
    float lr = lam[2 * p], li = lam[2 * p + 1];
    float2 s0 = sinv[(bl * NC + c) * P_ + p];
    float xr = s0.x, xi = s0.y;
    const unsigned* bp = Bu + ((size_t)(bl * L_ + c * LC)) * 256 + p;
    unsigned* xp = xb + ((size_t)(bl * L_ + c * LC)) * 256 + p;
    #pragma unroll 8
    for (int j = 0; j < LC; ++j) {
        unsigned wv = bp[(size_t)j * 256];
        float ur = __uint_as_float(wv << 16);
        float ui = __uint_as_float(wv & 0xffff0000u);
        float nr = lr * xr - li * xi + ur;
        float ni = lr * xi + li * xr + ui;
        xr = nr; xi = ni;
        xp[(size_t)j * 256] = pack_bf16x2(xr, xi);
    }
}

// ---------------- G2: y = x * C2op^T + D*u ----------------
// A: xb [MSEG][512] bf16 packed; B: C2op [256][512]; out fp32 [MSEG][256]
__global__ __launch_bounds__(256) void g2_gemm(
    const unsigned short* __restrict__ xb,
    const unsigned short* __restrict__ C2op,
    const float* __restrict__ useg, const float* __restrict__ Dv,
    float* __restrict__ yseg)
{
    __shared__ unsigned short Al[64 * 64];    // 8KB swizzled
    __shared__ unsigned short Bl[128 * 64];   // 16KB swizzled
    int tid = threadIdx.x, w = tid >> 6, lane = tid & 63;
    int wr = w >> 1, wc = w & 1;
    int m0 = blockIdx.x * 64;
    int n0 = blockIdx.y * 128;
    int lr_ = lane & 15, lk = lane >> 4;

    f32x4 acc[2][4];
    #pragma unroll
    for (int m = 0; m < 2; ++m)
        #pragma unroll
        for (int n = 0; n < 4; ++n)
            acc[m][n] = (f32x4){0.f, 0.f, 0.f, 0.f};

    int sw8 = ((lane & 7) ^ ((lane >> 3) & 7)) * 8;
    for (int kt = 0; kt < 8; ++kt) {
        int k0 = kt * 64;
        #pragma unroll
        for (int i = 0; i < 2; ++i) {
            int blk = i * 4 + w;
            int r = blk * 8 + (lane >> 3);
            gl_lds16(xb + (size_t)(m0 + r) * 512 + k0 + sw8, Al + blk * 512);
        }
        #pragma unroll
        for (int i = 0; i < 4; ++i) {
            int blk = i * 4 + w;
            int r = blk * 8 + (lane >> 3);
            gl_lds16(C2op + (size_t)(n0 + r) * 512 + k0 + sw8, Bl + blk * 512);
        }
        __syncthreads();
        #pragma unroll
        for (int kk = 0; kk < 2; ++kk) {
            short8v a_[2], b_[4];
            #pragma unroll
            for (int m = 0; m < 2; ++m) {
                int row = wr * 32 + m * 16 + lr_;
                a_[m] = *(const short8v*)&Al[row * 64 + (((lk + 4 * kk) ^ (lr_ & 7)) * 8)];
            }
            #pragma unroll
            for (int n = 0; n < 4; ++n) {
                int row = wc * 64 + n * 16 + lr_;
                b_[n] = *(const short8v*)&Bl[row * 64 + (((lk + 4 * kk) ^ (lr_ & 7)) * 8)];
            }
            #pragma unroll
            for (int m = 0; m < 2; ++m)
                #pragma unroll
                for (int n = 0; n < 4; ++n)
                    acc[m][n] = __builtin_amdgcn_mfma_f32_16x16x32_bf16(a_[m], b_[n], acc[m][n], 0, 0, 0);
        }
        __syncthreads();
    }

    float d_[4];
    #pragma unroll
    for (int n = 0; n < 4; ++n) d_[n] = Dv[n0 + wc * 64 + n * 16 + lr_];
    #pragma unroll
    for (int m = 0; m < 2; ++m)
        #pragma unroll
        for (int n = 0; n < 4; ++n)
            #pragma unroll
            for (int i = 0; i < 4; ++i) {
                int row = m0 + wr * 32 + m * 16 + lk * 4 + i;
                int col = n0 + wc * 64 + n * 16 + lr_;
                size_t off = (size_t)row * 256 + col;
                yseg[off] = acc[m][n][i] + d_[n] * useg[off];
            }
}

// ---------------- launch ----------------
extern "C" void kernel_launch(void* const* d_in, const int* in_sizes, int n_in,
                              void* d_out, int out_size, void* d_ws, size_t ws_size,
                              hipStream_t stream) {
    (void)in_sizes; (void)n_in; (void)out_size; (void)ws_size;
    const float* u    = (const float*)d_in[0];
    const float* Lre  = (const float*)d_in[1];
    const float* Lim  = (const float*)d_in[2];
    const float* Bre  = (const float*)d_in[3];
    const float* Bim  = (const float*)d_in[4];
    const float* Cre  = (const float*)d_in[5];
    const float* Cim  = (const float*)d_in[6];
    const float* Dv   = (const float*)d_in[7];
    const float* lstep= (const float*)d_in[8];

    char* w0 = (char*)d_ws;
    float* lam   = (float*)w0;  w0 += 2048;
    float* lamLc = (float*)w0;  w0 += 2048;
    unsigned short* B1op = (unsigned short*)w0; w0 += 512 * 256 * 2;
    unsigned short* C2op = (unsigned short*)w0; w0 += 256 * 512 * 2;
    float2* sfin = (float2*)w0; w0 += (size_t)SEG * NC * P_ * 8;
    float2* sinv = (float2*)w0; w0 += (size_t)SEG * NC * P_ * 8;
    unsigned short* ub = (unsigned short*)w0; w0 += (size_t)MSEG * H_ * 2;
    unsigned* Bu = (unsigned*)w0; w0 += (size_t)MSEG * 256 * 4;
    unsigned* xb = (unsigned*)w0; w0 += (size_t)MSEG * 256 * 4;

    k0_pre<<<256, 256, 0, stream>>>(Lre, Lim, Bre, Bim, Cre, Cim, lstep,
                                    lam, lamLc, B1op, C2op);
    for (int s = 0; s < NSEG; ++s) {
        const float* us = u + (size_t)s * MSEG * H_;
        float* ys = (float*)d_out + (size_t)s * MSEG * H_;
        ku_conv<<<MSEG * H_ / 4 / 256, 256, 0, stream>>>(us, ub);
        g1_gemm<<<dim3(MSEG / 128, 4), 256, 0, stream>>>(ub, B1op, Bu);
        s1_scan<<<SEG * NC, 256, 0, stream>>>(Bu, lam, sfin);
        s2_chain<<<SEG, 256, 0, stream>>>(lamLc, sfin, sinv);
        s3_scan<<<SEG * NC, 256, 0, stream>>>(Bu, lam, sinv, xb);
        g2_gemm<<<dim3(MSEG / 64, 2), 256, 0, stream>>>((const unsigned short*)xb, C2op,
                                                        us, Dv, ys);
    }
}